// Round 1
// baseline (6047.233 us; speedup 1.0000x reference)
//
#include <hip/hip_runtime.h>

#define H 128
#define LPAD 132
#define BM 64

enum { MODE_ENC = 0, MODE_EDGE = 1, MODE_NODE = 2, MODE_DEC = 3 };

__device__ __forceinline__ void fma_row(float acc[4], float a, const float4& b) {
    acc[0] = fmaf(a, b.x, acc[0]);
    acc[1] = fmaf(a, b.y, acc[1]);
    acc[2] = fmaf(a, b.z, acc[2]);
    acc[3] = fmaf(a, b.w, acc[3]);
}

// acc[j][jj] += sum_k A[row0+j][k] * B[k*H + c0+jj]
__device__ __forceinline__ void gemm_seg(const float (*A)[LPAD], int K,
                                         const float* __restrict__ B,
                                         int row0, int c0, float acc[8][4]) {
    int k = 0;
    for (; k + 4 <= K; k += 4) {
        float4 b0 = *(const float4*)(B + (size_t)(k + 0) * H + c0);
        float4 b1 = *(const float4*)(B + (size_t)(k + 1) * H + c0);
        float4 b2 = *(const float4*)(B + (size_t)(k + 2) * H + c0);
        float4 b3 = *(const float4*)(B + (size_t)(k + 3) * H + c0);
#pragma unroll
        for (int j = 0; j < 8; ++j) {
            float4 a = *(const float4*)(&A[row0 + j][k]);
            fma_row(acc[j], a.x, b0);
            fma_row(acc[j], a.y, b1);
            fma_row(acc[j], a.z, b2);
            fma_row(acc[j], a.w, b3);
        }
    }
    for (; k < K; ++k) {
        float4 bv = *(const float4*)(B + (size_t)k * H + c0);
#pragma unroll
        for (int j = 0; j < 8; ++j) {
            float a = A[row0 + j][k];
            fma_row(acc[j], a, bv);
        }
    }
}

// One fused MLP stage over a 64-row tile.
// ENC : in0 = x [N,10]          -> out h[n] = LN(MLP(x))
// EDGE: in0 = h (gather via src/tgt), eattr -> atomicAdd(aggr[tgt], LN(MLP([h_tgt,h_src,attr])))
// NODE: in0 = h, in1 = aggr     -> h[n] += LN(MLP([h,aggr]))
// DEC : in0 = h                 -> out[n] = relu(h@w1+b1)@w2+b2   (OUT=3)
template <int MODE>
__global__ __launch_bounds__(256, 2) void mlp_kernel(
    const float* in0, const float* in1,
    const int* __restrict__ srcI, const int* __restrict__ tgtI,
    const float* __restrict__ eattr,
    const float* __restrict__ w1, const float* __restrict__ b1,
    const float* __restrict__ w2, const float* __restrict__ b2,
    const float* __restrict__ g, const float* __restrict__ be,
    float* outp, int nrows) {
    __shared__ __align__(16) float sA[2][BM][LPAD];
    __shared__ float sAttr[BM][4];
    __shared__ int sIdxS[BM], sIdxT[BM];

    const int tid = threadIdx.x;
    const int tr = tid >> 5;        // 0..7  (8 row-groups of 8 rows)
    const int tc = tid & 31;        // 0..31 (column groups of 4)
    const int c0 = tc * 4;
    const int row0 = tr * 8;
    const int r0 = blockIdx.x * BM;

    // ---------------- stage A tile ----------------
    if (MODE == MODE_EDGE) {
        if (tid < BM) {
            int e = r0 + tid;
            sIdxS[tid] = (e < nrows) ? srcI[e] : 0;
            sIdxT[tid] = (e < nrows) ? tgtI[e] : 0;
        }
        __syncthreads();
        for (int idx = tid; idx < BM * 32; idx += 256) {
            int r = idx >> 5, q = idx & 31;
            int e = r0 + r;
            float4 vi = make_float4(0.f, 0.f, 0.f, 0.f), vj = vi;
            if (e < nrows) {
                vi = ((const float4*)in0)[(size_t)sIdxT[r] * 32 + q];  // x_i = h[tgt]
                vj = ((const float4*)in0)[(size_t)sIdxS[r] * 32 + q];  // x_j = h[src]
            }
            *(float4*)&sA[0][r][q * 4] = vi;
            *(float4*)&sA[1][r][q * 4] = vj;
        }
        if (tid < BM * 3) {
            int r = tid / 3, c = tid - 3 * (tid / 3);
            int e = r0 + r;
            sAttr[r][c] = (e < nrows) ? eattr[(size_t)e * 3 + c] : 0.f;
        }
    } else if (MODE == MODE_ENC) {
        for (int idx = tid; idx < BM * 10; idx += 256) {
            int r = idx / 10, c = idx - 10 * (idx / 10);
            int n = r0 + r;
            sA[0][r][c] = (n < nrows) ? in0[(size_t)n * 10 + c] : 0.f;
        }
    } else {  // NODE / DEC
        for (int idx = tid; idx < BM * 32; idx += 256) {
            int r = idx >> 5, q = idx & 31;
            int n = r0 + r;
            float4 v0 = make_float4(0.f, 0.f, 0.f, 0.f), v1 = v0;
            if (n < nrows) {
                v0 = ((const float4*)in0)[(size_t)n * 32 + q];
                if (MODE == MODE_NODE) v1 = ((const float4*)in1)[(size_t)n * 32 + q];
            }
            *(float4*)&sA[0][r][q * 4] = v0;
            if (MODE == MODE_NODE) *(float4*)&sA[1][r][q * 4] = v1;
        }
    }
    __syncthreads();

    // ---------------- GEMM1 + ReLU ----------------
    float acc[8][4];
    {
        float4 bb = *(const float4*)&b1[c0];
#pragma unroll
        for (int j = 0; j < 8; ++j) {
            acc[j][0] = bb.x; acc[j][1] = bb.y; acc[j][2] = bb.z; acc[j][3] = bb.w;
        }
    }
    if (MODE == MODE_ENC) {
        gemm_seg(sA[0], 10, w1, row0, c0, acc);
    } else if (MODE == MODE_DEC) {
        gemm_seg(sA[0], H, w1, row0, c0, acc);
    } else {  // EDGE / NODE: two 128-row segments of w1
        gemm_seg(sA[0], H, w1, row0, c0, acc);
        gemm_seg(sA[1], H, w1 + (size_t)H * H, row0, c0, acc);
        if (MODE == MODE_EDGE) {
#pragma unroll
            for (int k = 0; k < 3; ++k) {
                float4 bv = *(const float4*)(w1 + (size_t)(2 * H + k) * H + c0);
#pragma unroll
                for (int j = 0; j < 8; ++j) fma_row(acc[j], sAttr[row0 + j][k], bv);
            }
        }
    }
#pragma unroll
    for (int j = 0; j < 8; ++j) {
        acc[j][0] = fmaxf(acc[j][0], 0.f);
        acc[j][1] = fmaxf(acc[j][1], 0.f);
        acc[j][2] = fmaxf(acc[j][2], 0.f);
        acc[j][3] = fmaxf(acc[j][3], 0.f);
    }

    __syncthreads();  // all GEMM1 LDS reads done before hid overwrites sA[0]
#pragma unroll
    for (int j = 0; j < 8; ++j)
        *(float4*)&sA[0][row0 + j][c0] = make_float4(acc[j][0], acc[j][1], acc[j][2], acc[j][3]);
    __syncthreads();

    // ---------------- GEMM2 ----------------
    if (MODE == MODE_DEC) {
        // out[r][o] = b2[o] + sum_i hid[r][i] * w2[i*3+o],  OUT = 3
        if (tid < BM * 3) {
            int r = tid / 3, o = tid - 3 * (tid / 3);
            int gr = r0 + r;
            float s = b2[o];
            for (int i = 0; i < H; ++i) s = fmaf(sA[0][r][i], w2[(size_t)i * 3 + o], s);
            if (gr < nrows) outp[(size_t)gr * 3 + o] = s;
        }
        return;
    }

    {
        float4 bb = *(const float4*)&b2[c0];
#pragma unroll
        for (int j = 0; j < 8; ++j) {
            acc[j][0] = bb.x; acc[j][1] = bb.y; acc[j][2] = bb.z; acc[j][3] = bb.w;
        }
    }
    gemm_seg(sA[0], H, w2, row0, c0, acc);

    // ---------------- LayerNorm + epilogue ----------------
    float4 g4 = *(const float4*)&g[c0];
    float4 be4 = *(const float4*)&be[c0];
#pragma unroll
    for (int j = 0; j < 8; ++j) {
        float s = acc[j][0] + acc[j][1] + acc[j][2] + acc[j][3];
        float q = acc[j][0] * acc[j][0] + acc[j][1] * acc[j][1] +
                  acc[j][2] * acc[j][2] + acc[j][3] * acc[j][3];
#pragma unroll
        for (int m = 1; m < 32; m <<= 1) {  // reduce across the 32 lanes of this tr-group
            s += __shfl_xor(s, m);
            q += __shfl_xor(q, m);
        }
        float mean = s * (1.0f / 128.0f);
        float var = q * (1.0f / 128.0f) - mean * mean;
        float inv = rsqrtf(var + 1e-5f);
        float v0 = (acc[j][0] - mean) * inv * g4.x + be4.x;
        float v1 = (acc[j][1] - mean) * inv * g4.y + be4.y;
        float v2 = (acc[j][2] - mean) * inv * g4.z + be4.z;
        float v3 = (acc[j][3] - mean) * inv * g4.w + be4.w;
        int r = row0 + j;
        int gr = r0 + r;
        if (gr >= nrows) continue;
        if (MODE == MODE_EDGE) {
            size_t base = (size_t)sIdxT[r] * H + c0;
            atomicAdd(&outp[base + 0], v0);
            atomicAdd(&outp[base + 1], v1);
            atomicAdd(&outp[base + 2], v2);
            atomicAdd(&outp[base + 3], v3);
        } else if (MODE == MODE_NODE) {
            size_t base = (size_t)gr * H + c0;
            float4 hv = *(const float4*)&in0[base];
            *(float4*)&outp[base] = make_float4(hv.x + v0, hv.y + v1, hv.z + v2, hv.w + v3);
        } else {  // ENC
            *(float4*)&outp[(size_t)gr * H + c0] = make_float4(v0, v1, v2, v3);
        }
    }
}

extern "C" void kernel_launch(void* const* d_in, const int* in_sizes, int n_in,
                              void* d_out, int out_size, void* d_ws, size_t ws_size,
                              hipStream_t stream) {
    const float* x       = (const float*)d_in[0];
    const int*   ei      = (const int*)d_in[1];
    const float* eattr   = (const float*)d_in[2];
    const float* enc_w1  = (const float*)d_in[3];
    const float* enc_b1  = (const float*)d_in[4];
    const float* enc_w2  = (const float*)d_in[5];
    const float* enc_b2  = (const float*)d_in[6];
    const float* enc_g   = (const float*)d_in[7];
    const float* enc_be  = (const float*)d_in[8];
    const float* edge_w1 = (const float*)d_in[9];
    const float* edge_b1 = (const float*)d_in[10];
    const float* edge_w2 = (const float*)d_in[11];
    const float* edge_b2 = (const float*)d_in[12];
    const float* edge_g  = (const float*)d_in[13];
    const float* edge_be = (const float*)d_in[14];
    const float* node_w1 = (const float*)d_in[15];
    const float* node_b1 = (const float*)d_in[16];
    const float* node_w2 = (const float*)d_in[17];
    const float* node_b2 = (const float*)d_in[18];
    const float* node_g  = (const float*)d_in[19];
    const float* node_be = (const float*)d_in[20];
    const float* dec_w1  = (const float*)d_in[21];
    const float* dec_b1  = (const float*)d_in[22];
    const float* dec_w2  = (const float*)d_in[23];
    const float* dec_b2  = (const float*)d_in[24];

    const int N = in_sizes[0] / 10;
    const int E = in_sizes[1] / 2;
    const int* srcI = ei;       // edge_index[0]
    const int* tgtI = ei + E;   // edge_index[1]

    float* h    = (float*)d_ws;               // [N,128]
    float* aggr = h + (size_t)N * H;          // [N,128]

    dim3 blk(256);
    int gN = (N + BM - 1) / BM;
    int gE = (E + BM - 1) / BM;

    mlp_kernel<MODE_ENC><<<gN, blk, 0, stream>>>(
        x, nullptr, nullptr, nullptr, nullptr,
        enc_w1, enc_b1, enc_w2, enc_b2, enc_g, enc_be, h, N);

    for (int l = 0; l < 4; ++l) {
        hipMemsetAsync(aggr, 0, (size_t)N * H * sizeof(float), stream);
        mlp_kernel<MODE_EDGE><<<gE, blk, 0, stream>>>(
            h, nullptr, srcI, tgtI, eattr,
            edge_w1 + (size_t)l * (2 * H + 3) * H, edge_b1 + (size_t)l * H,
            edge_w2 + (size_t)l * H * H, edge_b2 + (size_t)l * H,
            edge_g + (size_t)l * H, edge_be + (size_t)l * H, aggr, E);
        mlp_kernel<MODE_NODE><<<gN, blk, 0, stream>>>(
            h, aggr, nullptr, nullptr, nullptr,
            node_w1 + (size_t)l * (2 * H) * H, node_b1 + (size_t)l * H,
            node_w2 + (size_t)l * H * H, node_b2 + (size_t)l * H,
            node_g + (size_t)l * H, node_be + (size_t)l * H, h, N);
    }

    mlp_kernel<MODE_DEC><<<gN, blk, 0, stream>>>(
        h, nullptr, nullptr, nullptr, nullptr,
        dec_w1, dec_b1, dec_w2, dec_b2, nullptr, nullptr, (float*)d_out, N);
}

// Round 2
// 4258.569 us; speedup vs baseline: 1.4200x; 1.4200x over previous
//
#include <hip/hip_runtime.h>

#define H 128
#define LPAD 132
#define BM 64

typedef __attribute__((ext_vector_type(8))) short bf8;
typedef __attribute__((ext_vector_type(4))) float f4;
typedef __attribute__((ext_vector_type(4))) short s4;

__device__ __forceinline__ short f2bf(float f) {
    unsigned u = __float_as_uint(f);
    unsigned r = u + 0x7FFFu + ((u >> 16) & 1u);   // round-to-nearest-even
    return (short)(r >> 16);
}

// ================= weight packing =================
// packed[m][kc][lane][i] = bf16( W[kc*32 + (lane>>4)*8 + i][m*16 + (lane&15)] ), 0 if k>=K
__global__ void pack_w(const float* __restrict__ W, short* __restrict__ out, int K, int KC) {
    const int layer = blockIdx.z;
    const float* Wl = W + (size_t)layer * K * H;
    short* ol = out + (size_t)layer * 8 * KC * 512;
    const int total = 8 * KC * 512;
    for (int idx = blockIdx.x * blockDim.x + threadIdx.x; idx < total; idx += gridDim.x * blockDim.x) {
        int i = idx & 7;
        int lane = (idx >> 3) & 63;
        int v = idx >> 9;
        int kc = v % KC;
        int m = v / KC;
        int k = kc * 32 + (lane >> 4) * 8 + i;
        int c = m * 16 + (lane & 15);
        float val = (k < K) ? Wl[(size_t)k * H + c] : 0.f;
        ol[idx] = f2bf(val);
    }
}

__global__ void pack_attr(const float* __restrict__ ea, short* __restrict__ out, int E) {
    int e = blockIdx.x * blockDim.x + threadIdx.x;
    if (e >= E) return;
    bf8 vv = {};
    vv[0] = f2bf(ea[(size_t)e * 3 + 0]);
    vv[1] = f2bf(ea[(size_t)e * 3 + 1]);
    vv[2] = f2bf(ea[(size_t)e * 3 + 2]);
    *(bf8*)(out + (size_t)e * 8) = vv;
}

// ================= fused MFMA edge/node MLP =================
// Swapped orientation: D1T[c][e] = sum_k W1[k][c] * in[e][k].
// MODE 1 = EDGE: in = [h_bf[tgt] | h_bf[src] | attr], epilogue atomicAdd(aggr[tgt]).
// MODE 2 = NODE: in = [h_bf[n] | aggr_f32[n]],        epilogue h[n] += LN(..), write h_bf.
template <int MODE>
__global__ __launch_bounds__(512, 2) void gnn_mfma(
    const short* __restrict__ hbf, const float* __restrict__ aggrf,
    const short* __restrict__ attrbf,
    const int* __restrict__ srcI, const int* __restrict__ tgtI,
    const short* __restrict__ w1p, const short* __restrict__ w2p,
    const float* __restrict__ b1, const float* __restrict__ b2,
    const float* __restrict__ gamma, const float* __restrict__ beta,
    float* __restrict__ outp, short* __restrict__ hbfout, int nrows) {
    constexpr int KC1 = (MODE == 1) ? 9 : 8;
    __shared__ __align__(16) short sW1[8 * KC1 * 512];
    __shared__ __align__(16) short sW2[8 * 4 * 512];

    const int tid = threadIdx.x;
    // stage packed weights to LDS (once per block)
    {
        const uint4* s1 = (const uint4*)w1p;
        uint4* d1 = (uint4*)sW1;
        for (int t = tid; t < 8 * KC1 * 512 / 8; t += 512) d1[t] = s1[t];
        const uint4* s2 = (const uint4*)w2p;
        uint4* d2 = (uint4*)sW2;
        for (int t = tid; t < 8 * 4 * 512 / 8; t += 512) d2[t] = s2[t];
    }
    __syncthreads();

    const int lane = tid & 63;
    const int wv = tid >> 6;          // 0..7
    const int g = lane >> 4;          // 0..3
    const int er = lane & 15;
    const int e = blockIdx.x * 128 + wv * 16 + er;
    const bool valid = e < nrows;
    const int eC = valid ? e : 0;

    int tS = 0, tT = eC;
    if (MODE == 1) { tS = srcI[eC]; tT = tgtI[eC]; }

    const bf8* rT = (const bf8*)(hbf + (size_t)tT * H);

    // ---------- GEMM1 (swapped): acc1[m] holds hidT[c = m*16+4g+r][e] ----------
    f4 acc1[8] = {};
#pragma unroll
    for (int kc = 0; kc < 4; ++kc) {
        bf8 b = rT[kc * 4 + g];
#pragma unroll
        for (int m = 0; m < 8; ++m)
            acc1[m] = __builtin_amdgcn_mfma_f32_16x16x32_bf16(
                *(const bf8*)(sW1 + ((m * KC1 + kc) * 64 + lane) * 8), b, acc1[m], 0, 0, 0);
    }
    if (MODE == 1) {
        const bf8* rS = (const bf8*)(hbf + (size_t)tS * H);
#pragma unroll
        for (int kc = 4; kc < 8; ++kc) {
            bf8 b = rS[(kc - 4) * 4 + g];
#pragma unroll
            for (int m = 0; m < 8; ++m)
                acc1[m] = __builtin_amdgcn_mfma_f32_16x16x32_bf16(
                    *(const bf8*)(sW1 + ((m * KC1 + kc) * 64 + lane) * 8), b, acc1[m], 0, 0, 0);
        }
        bf8 b = {};
        if (g == 0) b = *(const bf8*)(attrbf + (size_t)eC * 8);
#pragma unroll
        for (int m = 0; m < 8; ++m)
            acc1[m] = __builtin_amdgcn_mfma_f32_16x16x32_bf16(
                *(const bf8*)(sW1 + ((m * KC1 + 8) * 64 + lane) * 8), b, acc1[m], 0, 0, 0);
    } else {
        const f4* ra = (const f4*)(aggrf + (size_t)eC * H);
#pragma unroll
        for (int kc = 4; kc < 8; ++kc) {
            f4 a0 = ra[(kc - 4) * 8 + g * 2];
            f4 a1 = ra[(kc - 4) * 8 + g * 2 + 1];
            bf8 b;
#pragma unroll
            for (int q = 0; q < 4; ++q) { b[q] = f2bf(a0[q]); b[4 + q] = f2bf(a1[q]); }
#pragma unroll
            for (int m = 0; m < 8; ++m)
                acc1[m] = __builtin_amdgcn_mfma_f32_16x16x32_bf16(
                    *(const bf8*)(sW1 + ((m * KC1 + kc) * 64 + lane) * 8), b, acc1[m], 0, 0, 0);
        }
    }

    // bias + relu -> h1[m][r] = hid[e][m*16+4g+r]  (hidT D-layout)
    float h1[8][4];
#pragma unroll
    for (int m = 0; m < 8; ++m) {
        f4 bb = *(const f4*)(b1 + m * 16 + 4 * g);
#pragma unroll
        for (int r = 0; r < 4; ++r) h1[m][r] = fmaxf(acc1[m][r] + bb[r], 0.f);
    }

    // ---------- GEMM2 (swapped): B-frags from h1 via shuffles ----------
    // need hid[e][c], c = kc2*32 + 8g + i  ->  src lane (l&15)+16*(2(g&1)+(i>>2)), reg m'=2kc2+(g>>1), r=i&3
    f4 acc2[8] = {};
#pragma unroll
    for (int kc2 = 0; kc2 < 4; ++kc2) {
        float tmp[8];
#pragma unroll
        for (int i = 0; i < 8; ++i) {
            int sl = er + 16 * (2 * (g & 1) + (i >> 2));
            float vlo = __shfl(h1[2 * kc2 + 0][i & 3], sl, 64);
            float vhi = __shfl(h1[2 * kc2 + 1][i & 3], sl, 64);
            tmp[i] = (g >> 1) ? vhi : vlo;
        }
        bf8 bfr;
#pragma unroll
        for (int i = 0; i < 8; ++i) bfr[i] = f2bf(tmp[i]);
#pragma unroll
        for (int m = 0; m < 8; ++m)
            acc2[m] = __builtin_amdgcn_mfma_f32_16x16x32_bf16(
                *(const bf8*)(sW2 + ((m * 4 + kc2) * 64 + lane) * 8), bfr, acc2[m], 0, 0, 0);
    }

    // ---------- bias2 + LayerNorm (lane holds 32 channels of edge e) ----------
    float o[8][4];
    float s = 0.f, q = 0.f;
#pragma unroll
    for (int m = 0; m < 8; ++m) {
        f4 bb = *(const f4*)(b2 + m * 16 + 4 * g);
#pragma unroll
        for (int r = 0; r < 4; ++r) {
            float v = acc2[m][r] + bb[r];
            o[m][r] = v; s += v; q += v * v;
        }
    }
    s += __shfl_xor(s, 16, 64); q += __shfl_xor(q, 16, 64);
    s += __shfl_xor(s, 32, 64); q += __shfl_xor(q, 32, 64);
    const float mean = s * (1.f / 128.f);
    const float inv = rsqrtf(q * (1.f / 128.f) - mean * mean + 1e-5f);

    if (!valid) return;
    if (MODE == 1) {
        float* base = outp + (size_t)tT * H;
#pragma unroll
        for (int m = 0; m < 8; ++m) {
            f4 gg = *(const f4*)(gamma + m * 16 + 4 * g);
            f4 be4 = *(const f4*)(beta + m * 16 + 4 * g);
#pragma unroll
            for (int r = 0; r < 4; ++r)
                atomicAdd(base + m * 16 + 4 * g + r, (o[m][r] - mean) * inv * gg[r] + be4[r]);
        }
    } else {
        float* hp = outp + (size_t)eC * H;
        short* hb = hbfout + (size_t)eC * H;
#pragma unroll
        for (int m = 0; m < 8; ++m) {
            f4 gg = *(const f4*)(gamma + m * 16 + 4 * g);
            f4 be4 = *(const f4*)(beta + m * 16 + 4 * g);
            f4 hv = *(const f4*)(hp + m * 16 + 4 * g);
            f4 nv; s4 pk;
#pragma unroll
            for (int r = 0; r < 4; ++r) {
                nv[r] = hv[r] + (o[m][r] - mean) * inv * gg[r] + be4[r];
                pk[r] = f2bf(nv[r]);
            }
            *(f4*)(hp + m * 16 + 4 * g) = nv;
            *(s4*)(hb + m * 16 + 4 * g) = pk;
        }
    }
}

// ================= fp32 ENC / DEC (small) =================
enum { MODE_ENC = 0, MODE_DEC = 3 };

__device__ __forceinline__ void fma_row(float acc[4], float a, const float4& b) {
    acc[0] = fmaf(a, b.x, acc[0]);
    acc[1] = fmaf(a, b.y, acc[1]);
    acc[2] = fmaf(a, b.z, acc[2]);
    acc[3] = fmaf(a, b.w, acc[3]);
}

__device__ __forceinline__ void gemm_seg(const float (*A)[LPAD], int K,
                                         const float* __restrict__ B,
                                         int row0, int c0, float acc[8][4]) {
    int k = 0;
    for (; k + 4 <= K; k += 4) {
        float4 b0 = *(const float4*)(B + (size_t)(k + 0) * H + c0);
        float4 b1 = *(const float4*)(B + (size_t)(k + 1) * H + c0);
        float4 b2 = *(const float4*)(B + (size_t)(k + 2) * H + c0);
        float4 b3 = *(const float4*)(B + (size_t)(k + 3) * H + c0);
#pragma unroll
        for (int j = 0; j < 8; ++j) {
            float4 a = *(const float4*)(&A[row0 + j][k]);
            fma_row(acc[j], a.x, b0);
            fma_row(acc[j], a.y, b1);
            fma_row(acc[j], a.z, b2);
            fma_row(acc[j], a.w, b3);
        }
    }
    for (; k < K; ++k) {
        float4 bv = *(const float4*)(B + (size_t)k * H + c0);
#pragma unroll
        for (int j = 0; j < 8; ++j) fma_row(acc[j], A[row0 + j][k], bv);
    }
}

template <int MODE>
__global__ __launch_bounds__(256, 2) void mlp_small(
    const float* __restrict__ in0,
    const float* __restrict__ w1, const float* __restrict__ b1,
    const float* __restrict__ w2, const float* __restrict__ b2,
    const float* __restrict__ g, const float* __restrict__ be,
    float* __restrict__ outp, short* __restrict__ hbfout, int nrows) {
    __shared__ __align__(16) float sA[BM][LPAD];

    const int tid = threadIdx.x;
    const int tr = tid >> 5, tc = tid & 31;
    const int c0 = tc * 4, row0 = tr * 8;
    const int r0 = blockIdx.x * BM;

    if (MODE == MODE_ENC) {
        for (int idx = tid; idx < BM * 10; idx += 256) {
            int r = idx / 10, c = idx - 10 * (idx / 10);
            int n = r0 + r;
            sA[r][c] = (n < nrows) ? in0[(size_t)n * 10 + c] : 0.f;
        }
    } else {
        for (int idx = tid; idx < BM * 32; idx += 256) {
            int r = idx >> 5, qq = idx & 31;
            int n = r0 + r;
            float4 v0 = make_float4(0.f, 0.f, 0.f, 0.f);
            if (n < nrows) v0 = ((const float4*)in0)[(size_t)n * 32 + qq];
            *(float4*)&sA[r][qq * 4] = v0;
        }
    }
    __syncthreads();

    float acc[8][4];
    {
        float4 bb = *(const float4*)&b1[c0];
#pragma unroll
        for (int j = 0; j < 8; ++j) { acc[j][0] = bb.x; acc[j][1] = bb.y; acc[j][2] = bb.z; acc[j][3] = bb.w; }
    }
    gemm_seg(sA, (MODE == MODE_ENC) ? 10 : H, w1, row0, c0, acc);
#pragma unroll
    for (int j = 0; j < 8; ++j)
#pragma unroll
        for (int r = 0; r < 4; ++r) acc[j][r] = fmaxf(acc[j][r], 0.f);

    __syncthreads();
#pragma unroll
    for (int j = 0; j < 8; ++j)
        *(float4*)&sA[row0 + j][c0] = make_float4(acc[j][0], acc[j][1], acc[j][2], acc[j][3]);
    __syncthreads();

    if (MODE == MODE_DEC) {
        if (tid < BM * 3) {
            int r = tid / 3, o = tid - 3 * (tid / 3);
            int gr = r0 + r;
            float sv = b2[o];
            for (int i = 0; i < H; ++i) sv = fmaf(sA[r][i], w2[(size_t)i * 3 + o], sv);
            if (gr < nrows) outp[(size_t)gr * 3 + o] = sv;
        }
        return;
    }

    {
        float4 bb = *(const float4*)&b2[c0];
#pragma unroll
        for (int j = 0; j < 8; ++j) { acc[j][0] = bb.x; acc[j][1] = bb.y; acc[j][2] = bb.z; acc[j][3] = bb.w; }
    }
    gemm_seg(sA, H, w2, row0, c0, acc);

    float4 g4 = *(const float4*)&g[c0];
    float4 be4 = *(const float4*)&be[c0];
#pragma unroll
    for (int j = 0; j < 8; ++j) {
        float s = acc[j][0] + acc[j][1] + acc[j][2] + acc[j][3];
        float q = acc[j][0] * acc[j][0] + acc[j][1] * acc[j][1] +
                  acc[j][2] * acc[j][2] + acc[j][3] * acc[j][3];
#pragma unroll
        for (int m = 1; m < 32; m <<= 1) { s += __shfl_xor(s, m); q += __shfl_xor(q, m); }
        float mean = s * (1.0f / 128.0f);
        float inv = rsqrtf(q * (1.0f / 128.0f) - mean * mean + 1e-5f);
        int gr = r0 + row0 + j;
        if (gr >= nrows) continue;
        float v0 = (acc[j][0] - mean) * inv * g4.x + be4.x;
        float v1 = (acc[j][1] - mean) * inv * g4.y + be4.y;
        float v2 = (acc[j][2] - mean) * inv * g4.z + be4.z;
        float v3 = (acc[j][3] - mean) * inv * g4.w + be4.w;
        *(float4*)&outp[(size_t)gr * H + c0] = make_float4(v0, v1, v2, v3);
        s4 pk = {f2bf(v0), f2bf(v1), f2bf(v2), f2bf(v3)};
        *(s4*)&hbfout[(size_t)gr * H + c0] = pk;
    }
}

// ================= launcher =================
extern "C" void kernel_launch(void* const* d_in, const int* in_sizes, int n_in,
                              void* d_out, int out_size, void* d_ws, size_t ws_size,
                              hipStream_t stream) {
    const float* x       = (const float*)d_in[0];
    const int*   ei      = (const int*)d_in[1];
    const float* eattr   = (const float*)d_in[2];
    const float* enc_w1  = (const float*)d_in[3];
    const float* enc_b1  = (const float*)d_in[4];
    const float* enc_w2  = (const float*)d_in[5];
    const float* enc_b2  = (const float*)d_in[6];
    const float* enc_g   = (const float*)d_in[7];
    const float* enc_be  = (const float*)d_in[8];
    const float* edge_w1 = (const float*)d_in[9];
    const float* edge_b1 = (const float*)d_in[10];
    const float* edge_w2 = (const float*)d_in[11];
    const float* edge_b2 = (const float*)d_in[12];
    const float* edge_g  = (const float*)d_in[13];
    const float* edge_be = (const float*)d_in[14];
    const float* node_w1 = (const float*)d_in[15];
    const float* node_b1 = (const float*)d_in[16];
    const float* node_w2 = (const float*)d_in[17];
    const float* node_b2 = (const float*)d_in[18];
    const float* node_g  = (const float*)d_in[19];
    const float* node_be = (const float*)d_in[20];
    const float* dec_w1  = (const float*)d_in[21];
    const float* dec_b1  = (const float*)d_in[22];
    const float* dec_w2  = (const float*)d_in[23];
    const float* dec_b2  = (const float*)d_in[24];

    const int N = in_sizes[0] / 10;
    const int E = in_sizes[1] / 2;
    const int* srcI = ei;
    const int* tgtI = ei + E;

    float* h    = (float*)d_ws;                 // [N,128] f32
    float* aggr = h + (size_t)N * H;            // [N,128] f32
    short* hbf   = (short*)(aggr + (size_t)N * H);  // [N,128] bf16
    short* attrb = hbf + (size_t)N * H;             // [E,8]  bf16
    short* ew1p  = attrb + (size_t)E * 8;           // [4][8*9*512]
    short* ew2p  = ew1p + (size_t)4 * 8 * 9 * 512;  // [4][8*4*512]
    short* nw1p  = ew2p + (size_t)4 * 8 * 4 * 512;  // [4][8*8*512]
    short* nw2p  = nw1p + (size_t)4 * 8 * 8 * 512;  // [4][8*4*512]

    // ---- one-time packs ----
    pack_w<<<dim3(72, 1, 4), 256, 0, stream>>>(edge_w1, ew1p, 2 * H + 3, 9);
    pack_w<<<dim3(32, 1, 4), 256, 0, stream>>>(edge_w2, ew2p, H, 4);
    pack_w<<<dim3(64, 1, 4), 256, 0, stream>>>(node_w1, nw1p, 2 * H, 8);
    pack_w<<<dim3(32, 1, 4), 256, 0, stream>>>(node_w2, nw2p, H, 4);
    pack_attr<<<(E + 255) / 256, 256, 0, stream>>>(eattr, attrb, E);

    const int gN64 = (N + BM - 1) / BM;
    mlp_small<MODE_ENC><<<gN64, 256, 0, stream>>>(
        x, enc_w1, enc_b1, enc_w2, enc_b2, enc_g, enc_be, h, hbf, N);

    const int gE = (E + 127) / 128;
    const int gNN = (N + 127) / 128;
    for (int l = 0; l < 4; ++l) {
        hipMemsetAsync(aggr, 0, (size_t)N * H * sizeof(float), stream);
        gnn_mfma<1><<<gE, 512, 0, stream>>>(
            hbf, nullptr, attrb, srcI, tgtI,
            ew1p + (size_t)l * 8 * 9 * 512, ew2p + (size_t)l * 8 * 4 * 512,
            edge_b1 + (size_t)l * H, edge_b2 + (size_t)l * H,
            edge_g + (size_t)l * H, edge_be + (size_t)l * H,
            aggr, nullptr, E);
        gnn_mfma<2><<<gNN, 512, 0, stream>>>(
            hbf, aggr, nullptr, nullptr, nullptr,
            nw1p + (size_t)l * 8 * 8 * 512, nw2p + (size_t)l * 8 * 4 * 512,
            node_b1 + (size_t)l * H, node_b2 + (size_t)l * H,
            node_g + (size_t)l * H, node_be + (size_t)l * H,
            h, hbf, N);
    }

    mlp_small<MODE_DEC><<<gN64, 256, 0, stream>>>(
        h, dec_w1, dec_b1, dec_w2, dec_b2, nullptr, nullptr, (float*)d_out, nullptr, N);
}

// Round 3
// 1235.022 us; speedup vs baseline: 4.8965x; 3.4482x over previous
//
#include <hip/hip_runtime.h>

#define H 128
#define LPAD 132
#define BM 64

typedef __attribute__((ext_vector_type(8))) short bf8;
typedef __attribute__((ext_vector_type(4))) float f4;
typedef __attribute__((ext_vector_type(4))) short s4;

__device__ __forceinline__ short f2bf(float f) {
    unsigned u = __float_as_uint(f);
    unsigned r = u + 0x7FFFu + ((u >> 16) & 1u);   // round-to-nearest-even
    return (short)(r >> 16);
}

// ================= weight packing =================
// packed[m][kc][lane][i] = bf16( W[kc*32 + (lane>>4)*8 + i][m*16 + (lane&15)] ), 0 if k>=K
__global__ void pack_w(const float* __restrict__ W, short* __restrict__ out, int K, int KC) {
    const int layer = blockIdx.z;
    const float* Wl = W + (size_t)layer * K * H;
    short* ol = out + (size_t)layer * 8 * KC * 512;
    const int total = 8 * KC * 512;
    for (int idx = blockIdx.x * blockDim.x + threadIdx.x; idx < total; idx += gridDim.x * blockDim.x) {
        int i = idx & 7;
        int lane = (idx >> 3) & 63;
        int v = idx >> 9;
        int kc = v % KC;
        int m = v / KC;
        int k = kc * 32 + (lane >> 4) * 8 + i;
        int c = m * 16 + (lane & 15);
        float val = (k < K) ? Wl[(size_t)k * H + c] : 0.f;
        ol[idx] = f2bf(val);
    }
}

__global__ void pack_attr(const float* __restrict__ ea, short* __restrict__ out, int E) {
    int e = blockIdx.x * blockDim.x + threadIdx.x;
    if (e >= E) return;
    bf8 vv = {};
    vv[0] = f2bf(ea[(size_t)e * 3 + 0]);
    vv[1] = f2bf(ea[(size_t)e * 3 + 1]);
    vv[2] = f2bf(ea[(size_t)e * 3 + 2]);
    *(bf8*)(out + (size_t)e * 8) = vv;
}

// ================= CSR build =================
__global__ void csr_count(const int* __restrict__ tgt, int* __restrict__ cnt, int E) {
    int e = blockIdx.x * blockDim.x + threadIdx.x;
    if (e < E) atomicAdd(&cnt[tgt[e]], 1);
}

#define SCAN_T 1024
__global__ __launch_bounds__(SCAN_T) void scan_excl(const int* __restrict__ cnt,
                                                    int* __restrict__ start, int n) {
    __shared__ int part[SCAN_T];
    int t = threadIdx.x;
    int chunk = (n + SCAN_T - 1) / SCAN_T;
    int lo = t * chunk, hi = min(lo + chunk, n);
    int s = 0;
    for (int i = lo; i < hi; ++i) s += cnt[i];
    part[t] = s;
    __syncthreads();
    for (int off = 1; off < SCAN_T; off <<= 1) {
        int v = (t >= off) ? part[t - off] : 0;
        __syncthreads();
        part[t] += v;
        __syncthreads();
    }
    int base = (t > 0) ? part[t - 1] : 0;   // exclusive prefix of this chunk
    for (int i = lo; i < hi; ++i) { start[i] = base; base += cnt[i]; }
}

// scatter: start[] becomes end-offsets after this (start[n] -> orig start[n+1])
__global__ void csr_scatter(const int* __restrict__ tgt, int* __restrict__ start,
                            int* __restrict__ eperm, int E) {
    int e = blockIdx.x * blockDim.x + threadIdx.x;
    if (e < E) { int p = atomicAdd(&start[tgt[e]], 1); eperm[p] = e; }
}

// ================= aggregation (segment sum of bf16 messages) =================
__global__ __launch_bounds__(512) void aggregate(const short* __restrict__ msg,
                                                 const int* __restrict__ start,
                                                 const int* __restrict__ eperm,
                                                 float* __restrict__ aggr, int N) {
    int w = (int)((blockIdx.x * 512 + threadIdx.x) >> 6);
    int lane = threadIdx.x & 63;
    if (w >= N) return;
    int lo = w ? start[w - 1] : 0;   // post-scatter: start[n-1] == orig start[n]
    int hi = start[w];
    float a0 = 0.f, a1 = 0.f;
    for (int j = lo; j < hi; ++j) {
        int e = eperm[j];
        unsigned u = *(const unsigned*)(msg + (size_t)e * 128 + lane * 2);
        a0 += __uint_as_float(u << 16);           // channel 2*lane
        a1 += __uint_as_float(u & 0xFFFF0000u);   // channel 2*lane+1
    }
    *(float2*)(aggr + (size_t)w * 128 + lane * 2) = make_float2(a0, a1);
}

// ================= fused MFMA edge/node MLP =================
// Swapped orientation: D1T[c][e] = sum_k W1[k][c] * in[e][k].
// MODE 1 = EDGE: in = [h_bf[tgt] | h_bf[src] | attr]
//                epilogue TP=1: msg[e] (bf16);  TP=0: atomicAdd(aggr[tgt], ...)
// MODE 2 = NODE: in = [h_bf[n] | aggr_f32[n]],  epilogue h[n] += LN(..), write h_bf.
template <int MODE, int TP>
__global__ __launch_bounds__(1024, 4) void gnn_mfma(
    const short* __restrict__ hbf, const float* __restrict__ aggrf,
    const short* __restrict__ attrbf,
    const int* __restrict__ srcI, const int* __restrict__ tgtI,
    const short* __restrict__ w1p, const short* __restrict__ w2p,
    const float* __restrict__ b1, const float* __restrict__ b2,
    const float* __restrict__ gamma, const float* __restrict__ beta,
    float* __restrict__ outp, short* __restrict__ hbfout,
    short* __restrict__ msgout, int nrows) {
    constexpr int KC1 = (MODE == 1) ? 9 : 8;
    __shared__ __align__(16) short sW1[8 * KC1 * 512];
    __shared__ __align__(16) short sW2[8 * 4 * 512];

    const int tid = threadIdx.x;
    {
        const uint4* s1 = (const uint4*)w1p;
        uint4* d1 = (uint4*)sW1;
        for (int t = tid; t < 8 * KC1 * 512 / 8; t += 1024) d1[t] = s1[t];
        const uint4* s2 = (const uint4*)w2p;
        uint4* d2 = (uint4*)sW2;
        for (int t = tid; t < 8 * 4 * 512 / 8; t += 1024) d2[t] = s2[t];
    }
    __syncthreads();

    const int lane = tid & 63;
    const int wv = tid >> 6;          // 0..15
    const int g = lane >> 4;          // 0..3
    const int er = lane & 15;
    const int e = blockIdx.x * 256 + wv * 16 + er;
    const bool valid = e < nrows;
    const int eC = valid ? e : 0;

    int tS = 0, tT = eC;
    if (MODE == 1) { tS = srcI[eC]; tT = tgtI[eC]; }

    const bf8* rT = (const bf8*)(hbf + (size_t)tT * H);

    // ---------- GEMM1 (swapped): acc1[m] holds hidT[c = m*16+4g+r][e] ----------
    f4 acc1[8] = {};
#pragma unroll
    for (int kc = 0; kc < 4; ++kc) {
        bf8 b = rT[kc * 4 + g];
#pragma unroll
        for (int m = 0; m < 8; ++m)
            acc1[m] = __builtin_amdgcn_mfma_f32_16x16x32_bf16(
                *(const bf8*)(sW1 + ((m * KC1 + kc) * 64 + lane) * 8), b, acc1[m], 0, 0, 0);
    }
    if (MODE == 1) {
        const bf8* rS = (const bf8*)(hbf + (size_t)tS * H);
#pragma unroll
        for (int kc = 4; kc < 8; ++kc) {
            bf8 b = rS[(kc - 4) * 4 + g];
#pragma unroll
            for (int m = 0; m < 8; ++m)
                acc1[m] = __builtin_amdgcn_mfma_f32_16x16x32_bf16(
                    *(const bf8*)(sW1 + ((m * KC1 + kc) * 64 + lane) * 8), b, acc1[m], 0, 0, 0);
        }
        bf8 b = {};
        if (g == 0) b = *(const bf8*)(attrbf + (size_t)eC * 8);
#pragma unroll
        for (int m = 0; m < 8; ++m)
            acc1[m] = __builtin_amdgcn_mfma_f32_16x16x32_bf16(
                *(const bf8*)(sW1 + ((m * KC1 + 8) * 64 + lane) * 8), b, acc1[m], 0, 0, 0);
    } else {
        const f4* ra = (const f4*)(aggrf + (size_t)eC * H);
#pragma unroll
        for (int kc = 4; kc < 8; ++kc) {
            f4 a0 = ra[(kc - 4) * 8 + g * 2];
            f4 a1 = ra[(kc - 4) * 8 + g * 2 + 1];
            bf8 b;
#pragma unroll
            for (int q = 0; q < 4; ++q) { b[q] = f2bf(a0[q]); b[4 + q] = f2bf(a1[q]); }
#pragma unroll
            for (int m = 0; m < 8; ++m)
                acc1[m] = __builtin_amdgcn_mfma_f32_16x16x32_bf16(
                    *(const bf8*)(sW1 + ((m * KC1 + kc) * 64 + lane) * 8), b, acc1[m], 0, 0, 0);
        }
    }

    // bias + relu -> h1[m][r] = hid[e][m*16+4g+r]
    float h1[8][4];
#pragma unroll
    for (int m = 0; m < 8; ++m) {
        f4 bb = *(const f4*)(b1 + m * 16 + 4 * g);
#pragma unroll
        for (int r = 0; r < 4; ++r) h1[m][r] = fmaxf(acc1[m][r] + bb[r], 0.f);
    }

    // ---------- GEMM2 (swapped): B-frags from h1 via shuffles ----------
    f4 acc2[8] = {};
#pragma unroll
    for (int kc2 = 0; kc2 < 4; ++kc2) {
        float tmp[8];
#pragma unroll
        for (int i = 0; i < 8; ++i) {
            int sl = er + 16 * (2 * (g & 1) + (i >> 2));
            float vlo = __shfl(h1[2 * kc2 + 0][i & 3], sl, 64);
            float vhi = __shfl(h1[2 * kc2 + 1][i & 3], sl, 64);
            tmp[i] = (g >> 1) ? vhi : vlo;
        }
        bf8 bfr;
#pragma unroll
        for (int i = 0; i < 8; ++i) bfr[i] = f2bf(tmp[i]);
#pragma unroll
        for (int m = 0; m < 8; ++m)
            acc2[m] = __builtin_amdgcn_mfma_f32_16x16x32_bf16(
                *(const bf8*)(sW2 + ((m * 4 + kc2) * 64 + lane) * 8), bfr, acc2[m], 0, 0, 0);
    }

    // ---------- bias2 + LayerNorm ----------
    float o[8][4];
    float s = 0.f, q = 0.f;
#pragma unroll
    for (int m = 0; m < 8; ++m) {
        f4 bb = *(const f4*)(b2 + m * 16 + 4 * g);
#pragma unroll
        for (int r = 0; r < 4; ++r) {
            float v = acc2[m][r] + bb[r];
            o[m][r] = v; s += v; q += v * v;
        }
    }
    s += __shfl_xor(s, 16, 64); q += __shfl_xor(q, 16, 64);
    s += __shfl_xor(s, 32, 64); q += __shfl_xor(q, 32, 64);
    const float mean = s * (1.f / 128.f);
    const float inv = rsqrtf(q * (1.f / 128.f) - mean * mean + 1e-5f);

    if (!valid) return;
    if (MODE == 1) {
        if (TP) {
            short* mrow = msgout + (size_t)eC * H;
#pragma unroll
            for (int m = 0; m < 8; ++m) {
                f4 gg = *(const f4*)(gamma + m * 16 + 4 * g);
                f4 be4 = *(const f4*)(beta + m * 16 + 4 * g);
                s4 pk;
#pragma unroll
                for (int r = 0; r < 4; ++r)
                    pk[r] = f2bf((o[m][r] - mean) * inv * gg[r] + be4[r]);
                *(s4*)(mrow + m * 16 + 4 * g) = pk;
            }
        } else {
            float* base = outp + (size_t)tT * H;
#pragma unroll
            for (int m = 0; m < 8; ++m) {
                f4 gg = *(const f4*)(gamma + m * 16 + 4 * g);
                f4 be4 = *(const f4*)(beta + m * 16 + 4 * g);
#pragma unroll
                for (int r = 0; r < 4; ++r)
                    atomicAdd(base + m * 16 + 4 * g + r, (o[m][r] - mean) * inv * gg[r] + be4[r]);
            }
        }
    } else {
        float* hp = outp + (size_t)eC * H;
        short* hb = hbfout + (size_t)eC * H;
#pragma unroll
        for (int m = 0; m < 8; ++m) {
            f4 gg = *(const f4*)(gamma + m * 16 + 4 * g);
            f4 be4 = *(const f4*)(beta + m * 16 + 4 * g);
            f4 hv = *(const f4*)(hp + m * 16 + 4 * g);
            f4 nv; s4 pk;
#pragma unroll
            for (int r = 0; r < 4; ++r) {
                nv[r] = hv[r] + (o[m][r] - mean) * inv * gg[r] + be4[r];
                pk[r] = f2bf(nv[r]);
            }
            *(f4*)(hp + m * 16 + 4 * g) = nv;
            *(s4*)(hb + m * 16 + 4 * g) = pk;
        }
    }
}

// ================= fp32 ENC / DEC (small) =================
enum { MODE_ENC = 0, MODE_DEC = 3 };

__device__ __forceinline__ void fma_row(float acc[4], float a, const float4& b) {
    acc[0] = fmaf(a, b.x, acc[0]);
    acc[1] = fmaf(a, b.y, acc[1]);
    acc[2] = fmaf(a, b.z, acc[2]);
    acc[3] = fmaf(a, b.w, acc[3]);
}

__device__ __forceinline__ void gemm_seg(const float (*A)[LPAD], int K,
                                         const float* __restrict__ B,
                                         int row0, int c0, float acc[8][4]) {
    int k = 0;
    for (; k + 4 <= K; k += 4) {
        float4 b0 = *(const float4*)(B + (size_t)(k + 0) * H + c0);
        float4 b1 = *(const float4*)(B + (size_t)(k + 1) * H + c0);
        float4 b2 = *(const float4*)(B + (size_t)(k + 2) * H + c0);
        float4 b3 = *(const float4*)(B + (size_t)(k + 3) * H + c0);
#pragma unroll
        for (int j = 0; j < 8; ++j) {
            float4 a = *(const float4*)(&A[row0 + j][k]);
            fma_row(acc[j], a.x, b0);
            fma_row(acc[j], a.y, b1);
            fma_row(acc[j], a.z, b2);
            fma_row(acc[j], a.w, b3);
        }
    }
    for (; k < K; ++k) {
        float4 bv = *(const float4*)(B + (size_t)k * H + c0);
#pragma unroll
        for (int j = 0; j < 8; ++j) fma_row(acc[j], A[row0 + j][k], bv);
    }
}

template <int MODE>
__global__ __launch_bounds__(256, 2) void mlp_small(
    const float* __restrict__ in0,
    const float* __restrict__ w1, const float* __restrict__ b1,
    const float* __restrict__ w2, const float* __restrict__ b2,
    const float* __restrict__ g, const float* __restrict__ be,
    float* __restrict__ outp, short* __restrict__ hbfout, int nrows) {
    __shared__ __align__(16) float sA[BM][LPAD];

    const int tid = threadIdx.x;
    const int tr = tid >> 5, tc = tid & 31;
    const int c0 = tc * 4, row0 = tr * 8;
    const int r0 = blockIdx.x * BM;

    if (MODE == MODE_ENC) {
        for (int idx = tid; idx < BM * 10; idx += 256) {
            int r = idx / 10, c = idx - 10 * (idx / 10);
            int n = r0 + r;
            sA[r][c] = (n < nrows) ? in0[(size_t)n * 10 + c] : 0.f;
        }
    } else {
        for (int idx = tid; idx < BM * 32; idx += 256) {
            int r = idx >> 5, qq = idx & 31;
            int n = r0 + r;
            float4 v0 = make_float4(0.f, 0.f, 0.f, 0.f);
            if (n < nrows) v0 = ((const float4*)in0)[(size_t)n * 32 + qq];
            *(float4*)&sA[r][qq * 4] = v0;
        }
    }
    __syncthreads();

    float acc[8][4];
    {
        float4 bb = *(const float4*)&b1[c0];
#pragma unroll
        for (int j = 0; j < 8; ++j) { acc[j][0] = bb.x; acc[j][1] = bb.y; acc[j][2] = bb.z; acc[j][3] = bb.w; }
    }
    gemm_seg(sA, (MODE == MODE_ENC) ? 10 : H, w1, row0, c0, acc);
#pragma unroll
    for (int j = 0; j < 8; ++j)
#pragma unroll
        for (int r = 0; r < 4; ++r) acc[j][r] = fmaxf(acc[j][r], 0.f);

    __syncthreads();
#pragma unroll
    for (int j = 0; j < 8; ++j)
        *(float4*)&sA[row0 + j][c0] = make_float4(acc[j][0], acc[j][1], acc[j][2], acc[j][3]);
    __syncthreads();

    if (MODE == MODE_DEC) {
        if (tid < BM * 3) {
            int r = tid / 3, o = tid - 3 * (tid / 3);
            int gr = r0 + r;
            float sv = b2[o];
            for (int i = 0; i < H; ++i) sv = fmaf(sA[r][i], w2[(size_t)i * 3 + o], sv);
            if (gr < nrows) outp[(size_t)gr * 3 + o] = sv;
        }
        return;
    }

    {
        float4 bb = *(const float4*)&b2[c0];
#pragma unroll
        for (int j = 0; j < 8; ++j) { acc[j][0] = bb.x; acc[j][1] = bb.y; acc[j][2] = bb.z; acc[j][3] = bb.w; }
    }
    gemm_seg(sA, H, w2, row0, c0, acc);

    float4 g4 = *(const float4*)&g[c0];
    float4 be4 = *(const float4*)&be[c0];
#pragma unroll
    for (int j = 0; j < 8; ++j) {
        float s = acc[j][0] + acc[j][1] + acc[j][2] + acc[j][3];
        float q = acc[j][0] * acc[j][0] + acc[j][1] * acc[j][1] +
                  acc[j][2] * acc[j][2] + acc[j][3] * acc[j][3];
#pragma unroll
        for (int m = 1; m < 32; m <<= 1) { s += __shfl_xor(s, m); q += __shfl_xor(q, m); }
        float mean = s * (1.0f / 128.0f);
        float inv = rsqrtf(q * (1.0f / 128.0f) - mean * mean + 1e-5f);
        int gr = r0 + row0 + j;
        if (gr >= nrows) continue;
        float v0 = (acc[j][0] - mean) * inv * g4.x + be4.x;
        float v1 = (acc[j][1] - mean) * inv * g4.y + be4.y;
        float v2 = (acc[j][2] - mean) * inv * g4.z + be4.z;
        float v3 = (acc[j][3] - mean) * inv * g4.w + be4.w;
        *(float4*)&outp[(size_t)gr * H + c0] = make_float4(v0, v1, v2, v3);
        s4 pk = {f2bf(v0), f2bf(v1), f2bf(v2), f2bf(v3)};
        *(s4*)&hbfout[(size_t)gr * H + c0] = pk;
    }
}

// ================= launcher =================
static inline size_t align16(size_t x) { return (x + 15) & ~(size_t)15; }

extern "C" void kernel_launch(void* const* d_in, const int* in_sizes, int n_in,
                              void* d_out, int out_size, void* d_ws, size_t ws_size,
                              hipStream_t stream) {
    const float* x       = (const float*)d_in[0];
    const int*   ei      = (const int*)d_in[1];
    const float* eattr   = (const float*)d_in[2];
    const float* enc_w1  = (const float*)d_in[3];
    const float* enc_b1  = (const float*)d_in[4];
    const float* enc_w2  = (const float*)d_in[5];
    const float* enc_b2  = (const float*)d_in[6];
    const float* enc_g   = (const float*)d_in[7];
    const float* enc_be  = (const float*)d_in[8];
    const float* edge_w1 = (const float*)d_in[9];
    const float* edge_b1 = (const float*)d_in[10];
    const float* edge_w2 = (const float*)d_in[11];
    const float* edge_b2 = (const float*)d_in[12];
    const float* edge_g  = (const float*)d_in[13];
    const float* edge_be = (const float*)d_in[14];
    const float* node_w1 = (const float*)d_in[15];
    const float* node_b1 = (const float*)d_in[16];
    const float* node_w2 = (const float*)d_in[17];
    const float* node_b2 = (const float*)d_in[18];
    const float* node_g  = (const float*)d_in[19];
    const float* node_be = (const float*)d_in[20];
    const float* dec_w1  = (const float*)d_in[21];
    const float* dec_b1  = (const float*)d_in[22];
    const float* dec_w2  = (const float*)d_in[23];
    const float* dec_b2  = (const float*)d_in[24];

    const int N = in_sizes[0] / 10;
    const int E = in_sizes[1] / 2;
    const int* srcI = ei;
    const int* tgtI = ei + E;

    // ---- workspace layout ----
    char* base = (char*)d_ws;
    size_t off = 0;
    float* h    = (float*)(base + off); off = align16(off + (size_t)N * H * 4);
    float* aggr = (float*)(base + off); off = align16(off + (size_t)N * H * 4);
    short* hbf   = (short*)(base + off); off = align16(off + (size_t)N * H * 2);
    short* attrb = (short*)(base + off); off = align16(off + (size_t)E * 8 * 2);
    short* ew1p  = (short*)(base + off); off = align16(off + (size_t)4 * 8 * 9 * 512 * 2);
    short* ew2p  = (short*)(base + off); off = align16(off + (size_t)4 * 8 * 4 * 512 * 2);
    short* nw1p  = (short*)(base + off); off = align16(off + (size_t)4 * 8 * 8 * 512 * 2);
    short* nw2p  = (short*)(base + off); off = align16(off + (size_t)4 * 8 * 4 * 512 * 2);
    int*   cnt   = (int*)(base + off);  off = align16(off + (size_t)N * 4);
    int*   startp= (int*)(base + off);  off = align16(off + (size_t)(N + 1) * 4);
    int*   eperm = (int*)(base + off);  off = align16(off + (size_t)E * 4);
    short* msg   = (short*)(base + off);
    size_t need  = off + (size_t)E * H * 2;
    const bool two_phase = (ws_size >= need);

    // ---- one-time packs ----
    pack_w<<<dim3(72, 1, 4), 256, 0, stream>>>(edge_w1, ew1p, 2 * H + 3, 9);
    pack_w<<<dim3(32, 1, 4), 256, 0, stream>>>(edge_w2, ew2p, H, 4);
    pack_w<<<dim3(64, 1, 4), 256, 0, stream>>>(node_w1, nw1p, 2 * H, 8);
    pack_w<<<dim3(32, 1, 4), 256, 0, stream>>>(node_w2, nw2p, H, 4);
    pack_attr<<<(E + 255) / 256, 256, 0, stream>>>(eattr, attrb, E);

    // ---- CSR build (once per launch) ----
    if (two_phase) {
        hipMemsetAsync(cnt, 0, (size_t)N * 4, stream);
        csr_count<<<(E + 255) / 256, 256, 0, stream>>>(tgtI, cnt, E);
        scan_excl<<<1, SCAN_T, 0, stream>>>(cnt, startp, N);
        csr_scatter<<<(E + 255) / 256, 256, 0, stream>>>(tgtI, startp, eperm, E);
    }

    const int gN64 = (N + BM - 1) / BM;
    mlp_small<MODE_ENC><<<gN64, 256, 0, stream>>>(
        x, enc_w1, enc_b1, enc_w2, enc_b2, enc_g, enc_be, h, hbf, N);

    const int gE = (E + 255) / 256;
    const int gNN = (N + 255) / 256;
    const int gAg = (N + 7) / 8;
    for (int l = 0; l < 4; ++l) {
        if (two_phase) {
            gnn_mfma<1, 1><<<gE, 1024, 0, stream>>>(
                hbf, nullptr, attrb, srcI, tgtI,
                ew1p + (size_t)l * 8 * 9 * 512, ew2p + (size_t)l * 8 * 4 * 512,
                edge_b1 + (size_t)l * H, edge_b2 + (size_t)l * H,
                edge_g + (size_t)l * H, edge_be + (size_t)l * H,
                nullptr, nullptr, msg, E);
            aggregate<<<gAg, 512, 0, stream>>>(msg, startp, eperm, aggr, N);
        } else {
            hipMemsetAsync(aggr, 0, (size_t)N * H * sizeof(float), stream);
            gnn_mfma<1, 0><<<gE, 1024, 0, stream>>>(
                hbf, nullptr, attrb, srcI, tgtI,
                ew1p + (size_t)l * 8 * 9 * 512, ew2p + (size_t)l * 8 * 4 * 512,
                edge_b1 + (size_t)l * H, edge_b2 + (size_t)l * H,
                edge_g + (size_t)l * H, edge_be + (size_t)l * H,
                aggr, nullptr, nullptr, E);
        }
        gnn_mfma<2, 0><<<gNN, 1024, 0, stream>>>(
            hbf, aggr, nullptr, nullptr, nullptr,
            nw1p + (size_t)l * 8 * 8 * 512, nw2p + (size_t)l * 8 * 4 * 512,
            node_b1 + (size_t)l * H, node_b2 + (size_t)l * H,
            node_g + (size_t)l * H, node_be + (size_t)l * H,
            h, hbf, nullptr, N);
    }

    mlp_small<MODE_DEC><<<gN64, 256, 0, stream>>>(
        h, dec_w1, dec_b1, dec_w2, dec_b2, nullptr, nullptr, (float*)d_out, nullptr, N);
}

// Round 4
// 1031.557 us; speedup vs baseline: 5.8622x; 1.1972x over previous
//
#include <hip/hip_runtime.h>

#define H 128
#define LPAD 132
#define BM 64

typedef __attribute__((ext_vector_type(8))) short bf8;
typedef __attribute__((ext_vector_type(4))) float f4;
typedef __attribute__((ext_vector_type(4))) short s4;

__device__ __forceinline__ short f2bf(float f) {
    unsigned u = __float_as_uint(f);
    unsigned r = u + 0x7FFFu + ((u >> 16) & 1u);   // round-to-nearest-even
    return (short)(r >> 16);
}

// ================= weight packing =================
// packed[m][kc][lane][i] = bf16( W[kc*32 + (lane>>4)*8 + i][m*16 + (lane&15)] ), 0 if k>=K
__global__ void pack_w(const float* __restrict__ W, short* __restrict__ out, int K, int KC) {
    const int layer = blockIdx.z;
    const float* Wl = W + (size_t)layer * K * H;
    short* ol = out + (size_t)layer * 8 * KC * 512;
    const int total = 8 * KC * 512;
    for (int idx = blockIdx.x * blockDim.x + threadIdx.x; idx < total; idx += gridDim.x * blockDim.x) {
        int i = idx & 7;
        int lane = (idx >> 3) & 63;
        int v = idx >> 9;
        int kc = v % KC;
        int m = v / KC;
        int k = kc * 32 + (lane >> 4) * 8 + i;
        int c = m * 16 + (lane & 15);
        float val = (k < K) ? Wl[(size_t)k * H + c] : 0.f;
        ol[idx] = f2bf(val);
    }
}

// ================= CSR build =================
__global__ void csr_count(const int* __restrict__ tgt, int* __restrict__ cnt, int E) {
    int e = blockIdx.x * blockDim.x + threadIdx.x;
    if (e < E) atomicAdd(&cnt[tgt[e]], 1);
}

#define SCAN_T 1024
__global__ __launch_bounds__(SCAN_T) void scan_excl(const int* __restrict__ cnt,
                                                    int* __restrict__ start, int n) {
    __shared__ int part[SCAN_T];
    int t = threadIdx.x;
    int chunk = (n + SCAN_T - 1) / SCAN_T;
    int lo = t * chunk, hi = min(lo + chunk, n);
    int s = 0;
    for (int i = lo; i < hi; ++i) s += cnt[i];
    part[t] = s;
    __syncthreads();
    for (int off = 1; off < SCAN_T; off <<= 1) {
        int v = (t >= off) ? part[t - off] : 0;
        __syncthreads();
        part[t] += v;
        __syncthreads();
    }
    int base = (t > 0) ? part[t - 1] : 0;   // exclusive prefix of this chunk
    for (int i = lo; i < hi; ++i) { start[i] = base; base += cnt[i]; }
}

// scatter: start[] becomes end-offsets after this (start[n] -> orig start[n+1])
__global__ void csr_scatter(const int* __restrict__ tgt, int* __restrict__ start,
                            int* __restrict__ eperm, int E) {
    int e = blockIdx.x * blockDim.x + threadIdx.x;
    if (e < E) { int p = atomicAdd(&start[tgt[e]], 1); eperm[p] = e; }
}

// gather src/tgt/attr into sorted-by-tgt order (eperm==nullptr -> identity)
__global__ void reorder(const int* __restrict__ eperm,
                        const int* __restrict__ srcI, const int* __restrict__ tgtI,
                        const float* __restrict__ eattr,
                        int* __restrict__ srcs, int* __restrict__ tgts,
                        short* __restrict__ attrbS, int E) {
    int p = blockIdx.x * blockDim.x + threadIdx.x;
    if (p >= E) return;
    int e = eperm ? eperm[p] : p;
    srcs[p] = srcI[e];
    tgts[p] = tgtI[e];
    bf8 vv = {};
    vv[0] = f2bf(eattr[(size_t)e * 3 + 0]);
    vv[1] = f2bf(eattr[(size_t)e * 3 + 1]);
    vv[2] = f2bf(eattr[(size_t)e * 3 + 2]);
    *(bf8*)(attrbS + (size_t)p * 8) = vv;
}

// ================= aggregation: contiguous segment sum, bf16 out =================
__global__ __launch_bounds__(512) void aggregate_sorted(const short* __restrict__ msg,
                                                        const int* __restrict__ start,
                                                        short* __restrict__ aggrb, int N) {
    int w = (int)((blockIdx.x * 512 + threadIdx.x) >> 6);
    int lane = threadIdx.x & 63;
    if (w >= N) return;
    int lo = w ? start[w - 1] : 0;   // post-scatter: start[n-1] == orig start[n]
    int hi = start[w];
    float a0 = 0.f, a1 = 0.f;
    const unsigned* p = (const unsigned*)msg + lane;
    for (int j = lo; j < hi; ++j) {
        unsigned u = p[(size_t)j * 64];
        a0 += __uint_as_float(u << 16);           // channel 2*lane
        a1 += __uint_as_float(u & 0xFFFF0000u);   // channel 2*lane+1
    }
    unsigned pk = ((unsigned)(unsigned short)f2bf(a1) << 16) | (unsigned short)f2bf(a0);
    ((unsigned*)aggrb)[(size_t)w * 64 + lane] = pk;
}

// fallback: convert f32 aggr -> bf16
__global__ void cvt_aggr(const float* __restrict__ a, short* __restrict__ ab, int n2) {
    int i = blockIdx.x * blockDim.x + threadIdx.x;
    if (i >= n2) return;
    float2 v = ((const float2*)a)[i];
    ((unsigned*)ab)[i] = ((unsigned)(unsigned short)f2bf(v.y) << 16) | (unsigned short)f2bf(v.x);
}

// ================= fused MFMA edge/node MLP =================
// Swapped orientation: D1T[c][e] = sum_k W1[k][c] * in[e][k].
// MODE 1 = EDGE (inputs pre-sorted by tgt): in = [h_bf[tgts[p]] | h_bf[srcs[p]] | attr[p]]
//                epilogue TP=1: msg[p] (bf16, contiguous);  TP=0: atomicAdd(aggr[tgts[p]], ...)
// MODE 2 = NODE: in = [h_bf[n] | aggrb[n]],  epilogue h[n] += LN(..), write h_bf.
template <int MODE, int TP>
__global__ __launch_bounds__(1024, 4) void gnn_mfma(
    const short* __restrict__ hbf, const short* __restrict__ aggrb,
    const short* __restrict__ attrbf,
    const int* __restrict__ srcs, const int* __restrict__ tgts,
    const short* __restrict__ w1p, const short* __restrict__ w2p,
    const float* __restrict__ b1, const float* __restrict__ b2,
    const float* __restrict__ gamma, const float* __restrict__ beta,
    float* __restrict__ outp, short* __restrict__ hbfout,
    short* __restrict__ msgout, int nrows) {
    constexpr int KC1 = (MODE == 1) ? 9 : 8;
    __shared__ __align__(16) short sW1[8 * KC1 * 512];
    __shared__ __align__(16) short sW2[8 * 4 * 512];

    const int tid = threadIdx.x;
    {
        const uint4* s1 = (const uint4*)w1p;
        uint4* d1 = (uint4*)sW1;
        for (int t = tid; t < 8 * KC1 * 512 / 8; t += 1024) d1[t] = s1[t];
        const uint4* s2 = (const uint4*)w2p;
        uint4* d2 = (uint4*)sW2;
        for (int t = tid; t < 8 * 4 * 512 / 8; t += 1024) d2[t] = s2[t];
    }
    __syncthreads();

    const int lane = tid & 63;
    const int wv = tid >> 6;          // 0..15
    const int g = lane >> 4;          // 0..3
    const int er = lane & 15;
    const int e = blockIdx.x * 256 + wv * 16 + er;
    const bool valid = e < nrows;
    const int eC = valid ? e : 0;

    int tS = 0, tT = eC;
    if (MODE == 1) { tS = srcs[eC]; tT = tgts[eC]; }

    const bf8* rT = (const bf8*)(hbf + (size_t)tT * H);

    // ---------- GEMM1 (swapped): acc1[m] holds hidT[c = m*16+4g+r][e] ----------
    f4 acc1[8] = {};
#pragma unroll
    for (int kc = 0; kc < 4; ++kc) {
        bf8 b = rT[kc * 4 + g];
#pragma unroll
        for (int m = 0; m < 8; ++m)
            acc1[m] = __builtin_amdgcn_mfma_f32_16x16x32_bf16(
                *(const bf8*)(sW1 + ((m * KC1 + kc) * 64 + lane) * 8), b, acc1[m], 0, 0, 0);
    }
    {
        const bf8* rS = (MODE == 1) ? (const bf8*)(hbf + (size_t)tS * H)
                                    : (const bf8*)(aggrb + (size_t)eC * H);
#pragma unroll
        for (int kc = 4; kc < 8; ++kc) {
            bf8 b = rS[(kc - 4) * 4 + g];
#pragma unroll
            for (int m = 0; m < 8; ++m)
                acc1[m] = __builtin_amdgcn_mfma_f32_16x16x32_bf16(
                    *(const bf8*)(sW1 + ((m * KC1 + kc) * 64 + lane) * 8), b, acc1[m], 0, 0, 0);
        }
    }
    if (MODE == 1) {
        bf8 b = {};
        if (g == 0) b = *(const bf8*)(attrbf + (size_t)eC * 8);
#pragma unroll
        for (int m = 0; m < 8; ++m)
            acc1[m] = __builtin_amdgcn_mfma_f32_16x16x32_bf16(
                *(const bf8*)(sW1 + ((m * KC1 + 8) * 64 + lane) * 8), b, acc1[m], 0, 0, 0);
    }

    // bias + relu -> h1[m][r] = hid[e][m*16+4g+r]
    float h1[8][4];
#pragma unroll
    for (int m = 0; m < 8; ++m) {
        f4 bb = *(const f4*)(b1 + m * 16 + 4 * g);
#pragma unroll
        for (int r = 0; r < 4; ++r) h1[m][r] = fmaxf(acc1[m][r] + bb[r], 0.f);
    }

    // pack pairs: pk[m][hh] = {lo: bf16(h1[m][2hh]), hi: bf16(h1[m][2hh+1])}
    unsigned pk[8][2];
#pragma unroll
    for (int m = 0; m < 8; ++m)
#pragma unroll
        for (int hh = 0; hh < 2; ++hh)
            asm("v_cvt_pk_bf16_f32 %0, %1, %2"
                : "=v"(pk[m][hh]) : "v"(h1[m][2 * hh]), "v"(h1[m][2 * hh + 1]));

    // ---------- GEMM2 (swapped): B-frags via packed u32 shuffles ----------
    // dest lane l, bfr[2p..2p+1] <- pk[2kc2 + (g>>1)][p&1] from lane er+16*(2(g&1)+(p>>1))
    f4 acc2[8] = {};
#pragma unroll
    for (int kc2 = 0; kc2 < 4; ++kc2) {
        bf8 bfr;
        unsigned* bu = (unsigned*)&bfr;
#pragma unroll
        for (int p = 0; p < 4; ++p) {
            int sl = er + 16 * (2 * (g & 1) + (p >> 1));
            unsigned lo = (unsigned)__shfl((int)pk[2 * kc2 + 0][p & 1], sl, 64);
            unsigned hi = (unsigned)__shfl((int)pk[2 * kc2 + 1][p & 1], sl, 64);
            bu[p] = (g >> 1) ? hi : lo;
        }
#pragma unroll
        for (int m = 0; m < 8; ++m)
            acc2[m] = __builtin_amdgcn_mfma_f32_16x16x32_bf16(
                *(const bf8*)(sW2 + ((m * 4 + kc2) * 64 + lane) * 8), bfr, acc2[m], 0, 0, 0);
    }

    // ---------- bias2 + LayerNorm ----------
    float o[8][4];
    float s = 0.f, q = 0.f;
#pragma unroll
    for (int m = 0; m < 8; ++m) {
        f4 bb = *(const f4*)(b2 + m * 16 + 4 * g);
#pragma unroll
        for (int r = 0; r < 4; ++r) {
            float v = acc2[m][r] + bb[r];
            o[m][r] = v; s += v; q += v * v;
        }
    }
    s += __shfl_xor(s, 16, 64); q += __shfl_xor(q, 16, 64);
    s += __shfl_xor(s, 32, 64); q += __shfl_xor(q, 32, 64);
    const float mean = s * (1.f / 128.f);
    const float inv = rsqrtf(q * (1.f / 128.f) - mean * mean + 1e-5f);

    if (!valid) return;
    if (MODE == 1) {
        if (TP) {
            short* mrow = msgout + (size_t)eC * H;
#pragma unroll
            for (int m = 0; m < 8; ++m) {
                f4 gg = *(const f4*)(gamma + m * 16 + 4 * g);
                f4 be4 = *(const f4*)(beta + m * 16 + 4 * g);
                s4 pkk;
#pragma unroll
                for (int r = 0; r < 4; ++r)
                    pkk[r] = f2bf((o[m][r] - mean) * inv * gg[r] + be4[r]);
                *(s4*)(mrow + m * 16 + 4 * g) = pkk;
            }
        } else {
            float* base = outp + (size_t)tT * H;
#pragma unroll
            for (int m = 0; m < 8; ++m) {
                f4 gg = *(const f4*)(gamma + m * 16 + 4 * g);
                f4 be4 = *(const f4*)(beta + m * 16 + 4 * g);
#pragma unroll
                for (int r = 0; r < 4; ++r)
                    atomicAdd(base + m * 16 + 4 * g + r, (o[m][r] - mean) * inv * gg[r] + be4[r]);
            }
        }
    } else {
        float* hp = outp + (size_t)eC * H;
        short* hb = hbfout + (size_t)eC * H;
#pragma unroll
        for (int m = 0; m < 8; ++m) {
            f4 gg = *(const f4*)(gamma + m * 16 + 4 * g);
            f4 be4 = *(const f4*)(beta + m * 16 + 4 * g);
            f4 hv = *(const f4*)(hp + m * 16 + 4 * g);
            f4 nv; s4 pkk;
#pragma unroll
            for (int r = 0; r < 4; ++r) {
                nv[r] = hv[r] + (o[m][r] - mean) * inv * gg[r] + be4[r];
                pkk[r] = f2bf(nv[r]);
            }
            *(f4*)(hp + m * 16 + 4 * g) = nv;
            *(s4*)(hb + m * 16 + 4 * g) = pkk;
        }
    }
}

// ================= fp32 ENC / DEC (small) =================
enum { MODE_ENC = 0, MODE_DEC = 3 };

__device__ __forceinline__ void fma_row(float acc[4], float a, const float4& b) {
    acc[0] = fmaf(a, b.x, acc[0]);
    acc[1] = fmaf(a, b.y, acc[1]);
    acc[2] = fmaf(a, b.z, acc[2]);
    acc[3] = fmaf(a, b.w, acc[3]);
}

__device__ __forceinline__ void gemm_seg(const float (*A)[LPAD], int K,
                                         const float* __restrict__ B,
                                         int row0, int c0, float acc[8][4]) {
    int k = 0;
    for (; k + 4 <= K; k += 4) {
        float4 b0 = *(const float4*)(B + (size_t)(k + 0) * H + c0);
        float4 b1 = *(const float4*)(B + (size_t)(k + 1) * H + c0);
        float4 b2 = *(const float4*)(B + (size_t)(k + 2) * H + c0);
        float4 b3 = *(const float4*)(B + (size_t)(k + 3) * H + c0);
#pragma unroll
        for (int j = 0; j < 8; ++j) {
            float4 a = *(const float4*)(&A[row0 + j][k]);
            fma_row(acc[j], a.x, b0);
            fma_row(acc[j], a.y, b1);
            fma_row(acc[j], a.z, b2);
            fma_row(acc[j], a.w, b3);
        }
    }
    for (; k < K; ++k) {
        float4 bv = *(const float4*)(B + (size_t)k * H + c0);
#pragma unroll
        for (int j = 0; j < 8; ++j) fma_row(acc[j], A[row0 + j][k], bv);
    }
}

template <int MODE>
__global__ __launch_bounds__(256, 2) void mlp_small(
    const float* __restrict__ in0,
    const float* __restrict__ w1, const float* __restrict__ b1,
    const float* __restrict__ w2, const float* __restrict__ b2,
    const float* __restrict__ g, const float* __restrict__ be,
    float* __restrict__ outp, short* __restrict__ hbfout, int nrows) {
    __shared__ __align__(16) float sA[BM][LPAD];

    const int tid = threadIdx.x;
    const int tr = tid >> 5, tc = tid & 31;
    const int c0 = tc * 4, row0 = tr * 8;
    const int r0 = blockIdx.x * BM;

    if (MODE == MODE_ENC) {
        for (int idx = tid; idx < BM * 10; idx += 256) {
            int r = idx / 10, c = idx - 10 * (idx / 10);
            int n = r0 + r;
            sA[r][c] = (n < nrows) ? in0[(size_t)n * 10 + c] : 0.f;
        }
    } else {
        for (int idx = tid; idx < BM * 32; idx += 256) {
            int r = idx >> 5, qq = idx & 31;
            int n = r0 + r;
            float4 v0 = make_float4(0.f, 0.f, 0.f, 0.f);
            if (n < nrows) v0 = ((const float4*)in0)[(size_t)n * 32 + qq];
            *(float4*)&sA[r][qq * 4] = v0;
        }
    }
    __syncthreads();

    float acc[8][4];
    {
        float4 bb = *(const float4*)&b1[c0];
#pragma unroll
        for (int j = 0; j < 8; ++j) { acc[j][0] = bb.x; acc[j][1] = bb.y; acc[j][2] = bb.z; acc[j][3] = bb.w; }
    }
    gemm_seg(sA, (MODE == MODE_ENC) ? 10 : H, w1, row0, c0, acc);
#pragma unroll
    for (int j = 0; j < 8; ++j)
#pragma unroll
        for (int r = 0; r < 4; ++r) acc[j][r] = fmaxf(acc[j][r], 0.f);

    __syncthreads();
#pragma unroll
    for (int j = 0; j < 8; ++j)
        *(float4*)&sA[row0 + j][c0] = make_float4(acc[j][0], acc[j][1], acc[j][2], acc[j][3]);
    __syncthreads();

    if (MODE == MODE_DEC) {
        if (tid < BM * 3) {
            int r = tid / 3, o = tid - 3 * (tid / 3);
            int gr = r0 + r;
            float sv = b2[o];
            for (int i = 0; i < H; ++i) sv = fmaf(sA[r][i], w2[(size_t)i * 3 + o], sv);
            if (gr < nrows) outp[(size_t)gr * 3 + o] = sv;
        }
        return;
    }

    {
        float4 bb = *(const float4*)&b2[c0];
#pragma unroll
        for (int j = 0; j < 8; ++j) { acc[j][0] = bb.x; acc[j][1] = bb.y; acc[j][2] = bb.z; acc[j][3] = bb.w; }
    }
    gemm_seg(sA, H, w2, row0, c0, acc);

    float4 g4 = *(const float4*)&g[c0];
    float4 be4 = *(const float4*)&be[c0];
#pragma unroll
    for (int j = 0; j < 8; ++j) {
        float s = acc[j][0] + acc[j][1] + acc[j][2] + acc[j][3];
        float q = acc[j][0] * acc[j][0] + acc[j][1] * acc[j][1] +
                  acc[j][2] * acc[j][2] + acc[j][3] * acc[j][3];
#pragma unroll
        for (int m = 1; m < 32; m <<= 1) { s += __shfl_xor(s, m); q += __shfl_xor(q, m); }
        float mean = s * (1.0f / 128.0f);
        float inv = rsqrtf(q * (1.0f / 128.0f) - mean * mean + 1e-5f);
        int gr = r0 + row0 + j;
        if (gr >= nrows) continue;
        float v0 = (acc[j][0] - mean) * inv * g4.x + be4.x;
        float v1 = (acc[j][1] - mean) * inv * g4.y + be4.y;
        float v2 = (acc[j][2] - mean) * inv * g4.z + be4.z;
        float v3 = (acc[j][3] - mean) * inv * g4.w + be4.w;
        *(float4*)&outp[(size_t)gr * H + c0] = make_float4(v0, v1, v2, v3);
        s4 pk = {f2bf(v0), f2bf(v1), f2bf(v2), f2bf(v3)};
        *(s4*)&hbfout[(size_t)gr * H + c0] = pk;
    }
}

// ================= launcher =================
static inline size_t align16(size_t x) { return (x + 15) & ~(size_t)15; }

extern "C" void kernel_launch(void* const* d_in, const int* in_sizes, int n_in,
                              void* d_out, int out_size, void* d_ws, size_t ws_size,
                              hipStream_t stream) {
    const float* x       = (const float*)d_in[0];
    const int*   ei      = (const int*)d_in[1];
    const float* eattr   = (const float*)d_in[2];
    const float* enc_w1  = (const float*)d_in[3];
    const float* enc_b1  = (const float*)d_in[4];
    const float* enc_w2  = (const float*)d_in[5];
    const float* enc_b2  = (const float*)d_in[6];
    const float* enc_g   = (const float*)d_in[7];
    const float* enc_be  = (const float*)d_in[8];
    const float* edge_w1 = (const float*)d_in[9];
    const float* edge_b1 = (const float*)d_in[10];
    const float* edge_w2 = (const float*)d_in[11];
    const float* edge_b2 = (const float*)d_in[12];
    const float* edge_g  = (const float*)d_in[13];
    const float* edge_be = (const float*)d_in[14];
    const float* node_w1 = (const float*)d_in[15];
    const float* node_b1 = (const float*)d_in[16];
    const float* node_w2 = (const float*)d_in[17];
    const float* node_b2 = (const float*)d_in[18];
    const float* node_g  = (const float*)d_in[19];
    const float* node_be = (const float*)d_in[20];
    const float* dec_w1  = (const float*)d_in[21];
    const float* dec_b1  = (const float*)d_in[22];
    const float* dec_w2  = (const float*)d_in[23];
    const float* dec_b2  = (const float*)d_in[24];

    const int N = in_sizes[0] / 10;
    const int E = in_sizes[1] / 2;
    const int* srcI = ei;
    const int* tgtI = ei + E;

    // ---- workspace layout ----
    char* base = (char*)d_ws;
    size_t off = 0;
    float* h     = (float*)(base + off); off = align16(off + (size_t)N * H * 4);
    float* aggr  = (float*)(base + off); off = align16(off + (size_t)N * H * 4);
    short* aggrb = (short*)(base + off); off = align16(off + (size_t)N * H * 2);
    short* hbf   = (short*)(base + off); off = align16(off + (size_t)N * H * 2);
    short* attrb = (short*)(base + off); off = align16(off + (size_t)E * 8 * 2);
    short* ew1p  = (short*)(base + off); off = align16(off + (size_t)4 * 8 * 9 * 512 * 2);
    short* ew2p  = (short*)(base + off); off = align16(off + (size_t)4 * 8 * 4 * 512 * 2);
    short* nw1p  = (short*)(base + off); off = align16(off + (size_t)4 * 8 * 8 * 512 * 2);
    short* nw2p  = (short*)(base + off); off = align16(off + (size_t)4 * 8 * 4 * 512 * 2);
    int*   cnt   = (int*)(base + off);  off = align16(off + (size_t)N * 4);
    int*   startp= (int*)(base + off);  off = align16(off + (size_t)(N + 1) * 4);
    int*   eperm = (int*)(base + off);  off = align16(off + (size_t)E * 4);
    int*   srcs  = (int*)(base + off);  off = align16(off + (size_t)E * 4);
    int*   tgts  = (int*)(base + off);  off = align16(off + (size_t)E * 4);
    short* msg   = (short*)(base + off);
    size_t need  = off + (size_t)E * H * 2;
    const bool two_phase = (ws_size >= need);

    // ---- one-time packs ----
    pack_w<<<dim3(72, 1, 4), 256, 0, stream>>>(edge_w1, ew1p, 2 * H + 3, 9);
    pack_w<<<dim3(32, 1, 4), 256, 0, stream>>>(edge_w2, ew2p, H, 4);
    pack_w<<<dim3(64, 1, 4), 256, 0, stream>>>(node_w1, nw1p, 2 * H, 8);
    pack_w<<<dim3(32, 1, 4), 256, 0, stream>>>(node_w2, nw2p, H, 4);

    // ---- CSR build + sorted edge arrays (once per launch) ----
    if (two_phase) {
        hipMemsetAsync(cnt, 0, (size_t)N * 4, stream);
        csr_count<<<(E + 255) / 256, 256, 0, stream>>>(tgtI, cnt, E);
        scan_excl<<<1, SCAN_T, 0, stream>>>(cnt, startp, N);
        csr_scatter<<<(E + 255) / 256, 256, 0, stream>>>(tgtI, startp, eperm, E);
        reorder<<<(E + 255) / 256, 256, 0, stream>>>(eperm, srcI, tgtI, eattr, srcs, tgts, attrb, E);
    } else {
        reorder<<<(E + 255) / 256, 256, 0, stream>>>(nullptr, srcI, tgtI, eattr, srcs, tgts, attrb, E);
    }

    const int gN64 = (N + BM - 1) / BM;
    mlp_small<MODE_ENC><<<gN64, 256, 0, stream>>>(
        x, enc_w1, enc_b1, enc_w2, enc_b2, enc_g, enc_be, h, hbf, N);

    const int gE = (E + 255) / 256;
    const int gNN = (N + 255) / 256;
    const int gAg = (N + 7) / 8;
    for (int l = 0; l < 4; ++l) {
        if (two_phase) {
            gnn_mfma<1, 1><<<gE, 1024, 0, stream>>>(
                hbf, nullptr, attrb, srcs, tgts,
                ew1p + (size_t)l * 8 * 9 * 512, ew2p + (size_t)l * 8 * 4 * 512,
                edge_b1 + (size_t)l * H, edge_b2 + (size_t)l * H,
                edge_g + (size_t)l * H, edge_be + (size_t)l * H,
                nullptr, nullptr, msg, E);
            aggregate_sorted<<<gAg, 512, 0, stream>>>(msg, startp, aggrb, N);
        } else {
            hipMemsetAsync(aggr, 0, (size_t)N * H * sizeof(float), stream);
            gnn_mfma<1, 0><<<gE, 1024, 0, stream>>>(
                hbf, nullptr, attrb, srcs, tgts,
                ew1p + (size_t)l * 8 * 9 * 512, ew2p + (size_t)l * 8 * 4 * 512,
                edge_b1 + (size_t)l * H, edge_b2 + (size_t)l * H,
                edge_g + (size_t)l * H, edge_be + (size_t)l * H,
                aggr, nullptr, nullptr, E);
            cvt_aggr<<<(N * 64 + 255) / 256, 256, 0, stream>>>(aggr, aggrb, N * 64);
        }
        gnn_mfma<2, 0><<<gNN, 1024, 0, stream>>>(
            hbf, aggrb, nullptr, nullptr, nullptr,
            nw1p + (size_t)l * 8 * 8 * 512, nw2p + (size_t)l * 8 * 4 * 512,
            node_b1 + (size_t)l * H, node_b2 + (size_t)l * H,
            node_g + (size_t)l * H, node_be + (size_t)l * H,
            h, hbf, nullptr, N);
    }

    mlp_small<MODE_DEC><<<gN64, 256, 0, stream>>>(
        h, dec_w1, dec_b1, dec_w2, dec_b2, nullptr, nullptr, (float*)d_out, nullptr, N);
}